// Round 5
// baseline (104.664 us; speedup 1.0000x reference)
//
#include <hip/hip_runtime.h>
#include <stdint.h>

#define NBOX 6400
#define GRIDW 80
#define NC 20
#define NBLK 100   // NBOX / 64

__device__ __forceinline__ float sigmoidf(float x) { return 1.0f / (1.0f + expf(-x)); }

// Full per-box decode, exact reference formulas (outputs must be bit-faithful).
__device__ __forceinline__ void decode_one(const float* __restrict__ p, int n,
        float4* box, float* score, int* cls) {
    float conf = sigmoidf(p[0]);
    float c[NC];
    float m = -INFINITY;
    #pragma unroll
    for (int j = 0; j < NC; j++) { c[j] = p[1 + j]; m = fmaxf(m, c[j]); }
    float sum = 0.f;
    #pragma unroll
    for (int j = 0; j < NC; j++) { c[j] = expf(c[j] - m); sum += c[j]; }
    float best = -INFINITY; int bi = 0;
    #pragma unroll
    for (int j = 0; j < NC; j++) {
        float s = (c[j] / sum) * conf;        // softmax*conf, first-max argmax
        if (s > best) { best = s; bi = j; }
    }
    float gx = (float)(n / GRIDW);            // meshgrid 'ij': n = gx*80 + gy
    float gy = (float)(n % GRIDW);
    float cx = (gx + sigmoidf(p[21])) * 32.0f;
    float cy = (gy + sigmoidf(p[22])) * 32.0f;
    float w = expf(p[23]);
    float h = expf(p[24]);
    box->x = fminf(fmaxf((cx - w * 0.5f) / 2560.0f, 0.0f), 1.0f);
    box->y = fminf(fmaxf((cy - h * 0.5f) / 2560.0f, 0.0f), 1.0f);
    box->z = fminf(fmaxf((cx + w * 0.5f) / 2560.0f, 0.0f), 1.0f);
    box->w = fminf(fmaxf((cy + h * 0.5f) / 2560.0f, 0.0f), 1.0f);
    *score = best;
    *cls = bi;
}

// Dispatch 1 (25 x 256): decode + write all outputs (keep==valid provisional,
// exact when no suppressing pair exists) + per-64-chunk bbox (wave reduce) +
// valid ballot; zero-init flag/done.
__global__ __launch_bounds__(256) void k_decode(const float* __restrict__ pred,
        float* __restrict__ out, float4* __restrict__ boff,
        float* __restrict__ score_ws, float4* __restrict__ blkbb,
        uint64_t* __restrict__ validw, uint32_t* __restrict__ flag,
        uint32_t* __restrict__ done) {
    int t = threadIdx.x;
    int n = blockIdx.x * 256 + t;
    int l = t & 63;
    if (n == 0) { flag[0] = 0u; done[0] = 0u; }   // ws is poisoned each call
    float4 bx; float s; int cls;
    decode_one(pred + (size_t)n * 25, n, &bx, &s, &cls);
    ((float4*)out)[n] = bx;               // output 0: boxes
    out[32000 + n] = (float)cls;          // output 2: class_idx
    bool valid = s >= 0.01f;
    out[25600 + n] = valid ? s : 0.0f;    // output 1: scores*keep (fast path)
    out[38400 + n] = valid ? 1.0f : 0.0f; // output 3: keep (fast path)
    score_ws[n] = s;
    float off = 2.0f * (float)cls;        // class-offset trick (matches ref order)
    boff[n] = make_float4(bx.x + off, bx.y + off, bx.z + off, bx.w + off);

    // per-chunk bbox over valid boxes (un-offset geometry; conservative screen)
    float x1 = valid ? bx.x :  INFINITY;
    float y1 = valid ? bx.y :  INFINITY;
    float x2 = valid ? bx.z : -INFINITY;
    float y2 = valid ? bx.w : -INFINITY;
    #pragma unroll
    for (int d = 1; d < 64; d <<= 1) {
        x1 = fminf(x1, __shfl_xor(x1, d));
        y1 = fminf(y1, __shfl_xor(y1, d));
        x2 = fmaxf(x2, __shfl_xor(x2, d));
        y2 = fmaxf(y2, __shfl_xor(y2, d));
    }
    uint64_t vb = __ballot(valid);
    if (l == 0) {
        blkbb[n >> 6] = make_float4(x1, y1, x2, y2);
        validw[n >> 6] = vb;
    }
}

// Dispatch 2 (25 x 256): each wave owns row-block bi; lane-parallel bbox screen
// over all bj>=bi, then fine div-free conservative IoU>0.5 test for survivors
// (register shfl broadcast). Any possible hit -> flag bit. Last finishing block
// runs the exact NMS fallback iff flag set (never on this input).
__global__ __launch_bounds__(256) void k_work(const float4* __restrict__ boff,
        const float4* __restrict__ blkbb, const uint64_t* __restrict__ validw,
        const float* __restrict__ score, uint32_t* __restrict__ flag,
        uint32_t* __restrict__ done, int* __restrict__ sidx,
        float* __restrict__ sscore, float4* __restrict__ sbox,
        float* __restrict__ out) {
    __shared__ uint64_t klds[NBOX];       // 51.2 KB (fixup path only)
    __shared__ uint32_t keepb[NBOX / 32];
    __shared__ uint32_t lastf;
    int t = threadIdx.x;
    int w = t >> 6, l = t & 63;
    int bi = blockIdx.x * 4 + w;          // 0..99, one row-block per wave

    float4 ra = blkbb[bi];
    uint64_t rowvalid = validw[bi];
    const float M = 1e-5f;
    // screen bj = bi + l and bj = bi + 64 + l
    uint64_t surv_lo, surv_hi;
    {
        bool ov = false;
        int bj = bi + l;
        if (bj < NBLK) {
            float4 ca = blkbb[bj];
            ov = (fminf(ra.z, ca.z) + M >= fmaxf(ra.x, ca.x)) &&
                 (fminf(ra.w, ca.w) + M >= fmaxf(ra.y, ca.y));
        }
        surv_lo = __ballot(ov);
        ov = false;
        bj = bi + 64 + l;
        if (bj < NBLK) {
            float4 ca = blkbb[bj];
            ov = (fminf(ra.z, ca.z) + M >= fmaxf(ra.x, ca.x)) &&
                 (fminf(ra.w, ca.w) + M >= fmaxf(ra.y, ca.y));
        }
        surv_hi = __ballot(ov);
    }
    if (rowvalid == 0ull) { surv_lo = 0ull; surv_hi = 0ull; }

    int i = bi * 64 + l;
    float4 rb = boff[i];
    float areai = (rb.z - rb.x) * (rb.w - rb.y);
    bool rv = (rowvalid >> l) & 1ull;
    bool hit = false;
    while ((surv_lo | surv_hi) != 0ull) {
        int d;
        if (surv_lo) { d = __ffsll((unsigned long long)surv_lo) - 1; surv_lo &= surv_lo - 1; }
        else { d = 64 + __ffsll((unsigned long long)surv_hi) - 1; surv_hi &= surv_hi - 1; }
        int bj = bi + d;
        uint64_t colvalid = validw[bj];
        if (colvalid == 0ull) continue;
        float4 cb = boff[bj * 64 + l];    // lane l holds col box l of block bj
        if (rv && !hit) {
            for (int s2 = 0; s2 < 64; s2++) {
                if (!((colvalid >> s2) & 1ull)) continue;
                int j = bj * 64 + s2;
                if (bi == bj && j <= i) continue;     // unordered pairs once
                float bxx = __shfl(cb.x, s2);
                float byy = __shfl(cb.y, s2);
                float bzz = __shfl(cb.z, s2);
                float bww = __shfl(cb.w, s2);
                float xx1 = fmaxf(rb.x, bxx);
                float yy1 = fmaxf(rb.y, byy);
                float xx2 = fminf(rb.z, bzz);
                float yy2 = fminf(rb.w, bww);
                float ww = fmaxf(1e-28f, xx2 - xx1);  // EPS exactly as reference
                float hh = fmaxf(1e-28f, yy2 - yy1);
                float inter = ww * hh;
                float areaj = (bzz - bxx) * (bww - byy);
                // iou>0.5 <=> 3*inter > areai+areaj (denom>0); margin covers f32
                // rounding; also triggers on degenerate denom<=0 corners.
                if (3.0f * inter >= 0.9995f * (areai + areaj)) { hit = true; break; }
            }
        }
    }
    if (__ballot(hit) != 0ull && l == 0) atomicOr(flag, 1u);

    // ---- last-block-done: exact fallback only if any possible hit ----
    __syncthreads();
    __threadfence();
    if (t == 0) lastf = (atomicAdd(done, 1u) == 24u) ? 1u : 0u;
    __syncthreads();
    if (!lastf) return;
    uint32_t f;
    if (t == 0) { f = atomicOr(flag, 0u); lastf = f; }
    __syncthreads();
    if (!(lastf & 1u)) return;

    // ---- exact reference NMS (rank sort + sequential greedy), 256 threads ----
    for (int n = t; n < NBOX; n += 256)
        klds[n] = (((uint64_t)(~__float_as_uint(score[n]))) << 32) | (uint32_t)n;
    __syncthreads();
    for (int n = t; n < NBOX; n += 256) {
        uint64_t mk = klds[n];
        int r = 0;
        for (int j = 0; j < NBOX; j++) r += (klds[j] < mk) ? 1 : 0;
        sidx[r] = n;
        sscore[r] = score[n];
        sbox[r] = boff[n];
    }
    __syncthreads();
    for (int w2 = t; w2 < NBOX / 32; w2 += 256) {
        uint32_t v = 0;
        for (int b = 0; b < 32; b++) v |= (sscore[w2 * 32 + b] >= 0.01f) ? (1u << b) : 0u;
        keepb[w2] = v;
    }
    __syncthreads();
    for (int ii = 0; ii < NBOX; ii++) {
        bool kept = (keepb[ii >> 5] >> (ii & 31)) & 1u;   // uniform LDS broadcast
        if (kept) {
            float4 a = sbox[ii];
            float areaa = (a.z - a.x) * (a.w - a.y);
            for (int j = ii + 1 + t; j < NBOX; j += 256) {
                if ((keepb[j >> 5] >> (j & 31)) & 1u) {
                    float4 b = sbox[j];
                    float xx1 = fmaxf(a.x, b.x);
                    float yy1 = fmaxf(a.y, b.y);
                    float xx2 = fminf(a.z, b.z);
                    float yy2 = fminf(a.w, b.w);
                    float ww = fmaxf(1e-28f, xx2 - xx1);
                    float hh = fmaxf(1e-28f, yy2 - yy1);
                    float inter = ww * hh;
                    float areab = (b.z - b.x) * (b.w - b.y);
                    float iou = inter / (areaa + areab - inter);  // exact ref formula
                    if (iou > 0.5f) atomicAnd(&keepb[j >> 5], ~(1u << (j & 31)));
                }
            }
        }
        __syncthreads();
    }
    for (int r = t; r < NBOX; r += 256) {
        int orig = sidx[r];
        uint32_t kb = (keepb[r >> 5] >> (r & 31)) & 1u;
        out[38400 + orig] = (float)kb;
        out[25600 + orig] = kb ? sscore[r] : 0.0f;
    }
}

extern "C" void kernel_launch(void* const* d_in, const int* in_sizes, int n_in,
                              void* d_out, int out_size, void* d_ws, size_t ws_size,
                              hipStream_t stream) {
    const float* pred = (const float*)d_in[0];
    float* out = (float*)d_out;
    char* ws = (char*)d_ws;
    float4*   boff   = (float4*)(ws + 0);        // 6400 f4  (102400 B)
    float*    score  = (float*)(ws + 102400);    // 6400 f32
    float4*   blkbb  = (float4*)(ws + 128000);   // 100 f4 block bboxes
    uint64_t* validw = (uint64_t*)(ws + 129600); // 100 u64 valid ballots
    uint32_t* flag   = (uint32_t*)(ws + 130432); // 1 u32
    uint32_t* done   = (uint32_t*)(ws + 130436); // 1 u32
    int*      sidx   = (int*)(ws + 131072);      // slow path only
    float*    sscore = (float*)(ws + 156672);    // slow path only
    float4*   sbox   = (float4*)(ws + 182272);   // slow path only

    k_decode<<<25, 256, 0, stream>>>(pred, out, boff, score, blkbb, validw, flag, done);
    k_work<<<25, 256, 0, stream>>>(boff, blkbb, validw, score, flag, done,
                                   sidx, sscore, sbox, out);
}

// Round 6
// 66.167 us; speedup vs baseline: 1.5818x; 1.5818x over previous
//
#include <hip/hip_runtime.h>
#include <stdint.h>

#define NBOX 6400
#define GRIDW 80
#define NC 20
#define NBLK 100   // NBOX / 64

__device__ __forceinline__ float sigmoidf(float x) { return 1.0f / (1.0f + expf(-x)); }

// Full per-box decode, exact reference formulas (outputs must be bit-faithful).
__device__ __forceinline__ void decode_one(const float* __restrict__ p, int n,
        float4* box, float* score, int* cls) {
    float conf = sigmoidf(p[0]);
    float c[NC];
    float m = -INFINITY;
    #pragma unroll
    for (int j = 0; j < NC; j++) { c[j] = p[1 + j]; m = fmaxf(m, c[j]); }
    float sum = 0.f;
    #pragma unroll
    for (int j = 0; j < NC; j++) { c[j] = expf(c[j] - m); sum += c[j]; }
    float best = -INFINITY; int bi = 0;
    #pragma unroll
    for (int j = 0; j < NC; j++) {
        float s = (c[j] / sum) * conf;        // softmax*conf, first-max argmax
        if (s > best) { best = s; bi = j; }
    }
    float gx = (float)(n / GRIDW);            // meshgrid 'ij': n = gx*80 + gy
    float gy = (float)(n % GRIDW);
    float cx = (gx + sigmoidf(p[21])) * 32.0f;
    float cy = (gy + sigmoidf(p[22])) * 32.0f;
    float w = expf(p[23]);
    float h = expf(p[24]);
    box->x = fminf(fmaxf((cx - w * 0.5f) / 2560.0f, 0.0f), 1.0f);
    box->y = fminf(fmaxf((cy - h * 0.5f) / 2560.0f, 0.0f), 1.0f);
    box->z = fminf(fmaxf((cx + w * 0.5f) / 2560.0f, 0.0f), 1.0f);
    box->w = fminf(fmaxf((cy + h * 0.5f) / 2560.0f, 0.0f), 1.0f);
    *score = best;
    *cls = bi;
}

// Dispatch 1 (25 x 256): decode + write all outputs (keep==valid provisional,
// exact when no suppressing pair exists) + per-64-chunk bbox (wave reduce) +
// valid ballot; zero-init flag/done.
__global__ __launch_bounds__(256) void k_decode(const float* __restrict__ pred,
        float* __restrict__ out, float4* __restrict__ boff,
        float* __restrict__ score_ws, float4* __restrict__ blkbb,
        uint64_t* __restrict__ validw, uint32_t* __restrict__ flag,
        uint32_t* __restrict__ done) {
    int t = threadIdx.x;
    int n = blockIdx.x * 256 + t;
    int l = t & 63;
    if (n == 0) { flag[0] = 0u; done[0] = 0u; }   // ws is poisoned each call
    float4 bx; float s; int cls;
    decode_one(pred + (size_t)n * 25, n, &bx, &s, &cls);
    ((float4*)out)[n] = bx;               // output 0: boxes
    out[32000 + n] = (float)cls;          // output 2: class_idx
    bool valid = s >= 0.01f;
    out[25600 + n] = valid ? s : 0.0f;    // output 1: scores*keep (fast path)
    out[38400 + n] = valid ? 1.0f : 0.0f; // output 3: keep (fast path)
    score_ws[n] = s;
    float off = 2.0f * (float)cls;        // class-offset trick (matches ref order)
    boff[n] = make_float4(bx.x + off, bx.y + off, bx.z + off, bx.w + off);

    // per-chunk bbox over valid boxes (un-offset geometry; conservative screen —
    // cross-class pairs are handled exactly by the offset boxes in k_pairs)
    float x1 = valid ? bx.x :  INFINITY;
    float y1 = valid ? bx.y :  INFINITY;
    float x2 = valid ? bx.z : -INFINITY;
    float y2 = valid ? bx.w : -INFINITY;
    #pragma unroll
    for (int d = 1; d < 64; d <<= 1) {
        x1 = fminf(x1, __shfl_xor(x1, d));
        y1 = fminf(y1, __shfl_xor(y1, d));
        x2 = fmaxf(x2, __shfl_xor(x2, d));
        y2 = fmaxf(y2, __shfl_xor(y2, d));
    }
    uint64_t vb = __ballot(valid);
    if (l == 0) {
        blkbb[n >> 6] = make_float4(x1, y1, x2, y2);
        validw[n >> 6] = vb;
    }
}

// Dispatch 2 (100 x 256): block owns row-block bi. Lane-parallel bbox screen
// over bj>=bi; per surviving bj: stage 64 boxes in LDS, 4 waves each test a
// 16-column slice fully unrolled & branch-free (LDS uniform-address broadcast,
// no shfl chains). Any possible IoU>0.5 pair -> flag. Last finishing block
// runs the exact NMS fallback iff flag set (never on this input).
__global__ __launch_bounds__(256) void k_pairs(const float4* __restrict__ boff,
        const float4* __restrict__ blkbb, const uint64_t* __restrict__ validw,
        const float* __restrict__ score, uint32_t* __restrict__ flag,
        uint32_t* __restrict__ done, int* __restrict__ sidx,
        float* __restrict__ sscore, float4* __restrict__ sbox,
        float* __restrict__ out) {
    __shared__ float4 cblds[64];          // staged column boxes (offset coords)
    __shared__ uint64_t klds[NBOX];       // 51.2 KB, fallback path only
    __shared__ uint32_t keepb[NBOX / 32]; // fallback path only
    __shared__ uint32_t lastf;
    int t = threadIdx.x;
    int w = t >> 6, l = t & 63;
    int bi = blockIdx.x;

    float4 ra = blkbb[bi];
    uint64_t rowvalid = validw[bi];
    const float M = 1e-5f;
    // screen (identical ballots in every wave -> uniform survivor list)
    uint64_t surv_lo = 0ull, surv_hi = 0ull;
    if (rowvalid != 0ull) {
        bool ov = false;
        int bj = bi + l;
        if (bj < NBLK) {
            float4 ca = blkbb[bj];
            ov = (fminf(ra.z, ca.z) + M >= fmaxf(ra.x, ca.x)) &&
                 (fminf(ra.w, ca.w) + M >= fmaxf(ra.y, ca.y));
        }
        surv_lo = __ballot(ov);
        ov = false;
        bj = bi + 64 + l;
        if (bj < NBLK) {
            float4 ca = blkbb[bj];
            ov = (fminf(ra.z, ca.z) + M >= fmaxf(ra.x, ca.x)) &&
                 (fminf(ra.w, ca.w) + M >= fmaxf(ra.y, ca.y));
        }
        surv_hi = __ballot(ov);
    }

    int i = bi * 64 + l;                  // each wave covers all 64 rows
    float4 rb = boff[i];
    float areai = (rb.z - rb.x) * (rb.w - rb.y);
    bool rv = (rowvalid >> l) & 1ull;
    bool hit = false;
    while ((surv_lo | surv_hi) != 0ull) { // uniform across block
        int d;
        if (surv_lo) { d = __ffsll((unsigned long long)surv_lo) - 1; surv_lo &= surv_lo - 1; }
        else { d = 64 + __ffsll((unsigned long long)surv_hi) - 1; surv_hi &= surv_hi - 1; }
        int bj = bi + d;
        uint64_t colvalid = validw[bj];
        __syncthreads();
        if (t < 64) cblds[t] = boff[bj * 64 + t];
        __syncthreads();
        if (colvalid != 0ull) {
            #pragma unroll
            for (int k2 = 0; k2 < 16; k2++) {
                int s2 = w * 16 + k2;                 // wave-uniform column
                float4 b = cblds[s2];                 // LDS broadcast read
                bool ok = rv && ((colvalid >> s2) & 1ull) &&
                          !(bi == bj && s2 <= l);     // unordered pairs once
                float xx1 = fmaxf(rb.x, b.x);
                float yy1 = fmaxf(rb.y, b.y);
                float xx2 = fminf(rb.z, b.z);
                float yy2 = fminf(rb.w, b.w);
                float ww = fmaxf(1e-28f, xx2 - xx1);  // EPS exactly as reference
                float hh = fmaxf(1e-28f, yy2 - yy1);
                float inter = ww * hh;
                float areaj = (b.z - b.x) * (b.w - b.y);
                // iou>0.5 <=> 3*inter > areai+areaj (denom>0); margin covers f32
                // rounding; also triggers on degenerate denom<=0 corners.
                hit |= ok && (3.0f * inter >= 0.9995f * (areai + areaj));
            }
        }
    }
    if (__ballot(hit) != 0ull && l == 0) atomicOr(flag, 1u);

    // ---- last-block-done: exact fallback only if any possible hit ----
    __syncthreads();
    __threadfence();
    if (t == 0) lastf = (atomicAdd(done, 1u) == NBLK - 1) ? 1u : 0u;
    __syncthreads();
    if (!lastf) return;
    if (t == 0) lastf = atomicOr(flag, 0u);
    __syncthreads();
    if (!lastf) return;

    // ---- exact reference NMS (rank sort + sequential greedy), 256 threads ----
    for (int n = t; n < NBOX; n += 256)
        klds[n] = (((uint64_t)(~__float_as_uint(score[n]))) << 32) | (uint32_t)n;
    __syncthreads();
    for (int n = t; n < NBOX; n += 256) {
        uint64_t mk = klds[n];
        int r = 0;
        for (int j = 0; j < NBOX; j++) r += (klds[j] < mk) ? 1 : 0;
        sidx[r] = n;
        sscore[r] = score[n];
        sbox[r] = boff[n];
    }
    __syncthreads();
    for (int w2 = t; w2 < NBOX / 32; w2 += 256) {
        uint32_t v = 0;
        for (int b = 0; b < 32; b++) v |= (sscore[w2 * 32 + b] >= 0.01f) ? (1u << b) : 0u;
        keepb[w2] = v;
    }
    __syncthreads();
    for (int ii = 0; ii < NBOX; ii++) {
        bool kept = (keepb[ii >> 5] >> (ii & 31)) & 1u;   // uniform LDS broadcast
        if (kept) {
            float4 a = sbox[ii];
            float areaa = (a.z - a.x) * (a.w - a.y);
            for (int j = ii + 1 + t; j < NBOX; j += 256) {
                if ((keepb[j >> 5] >> (j & 31)) & 1u) {
                    float4 b = sbox[j];
                    float xx1 = fmaxf(a.x, b.x);
                    float yy1 = fmaxf(a.y, b.y);
                    float xx2 = fminf(a.z, b.z);
                    float yy2 = fminf(a.w, b.w);
                    float ww = fmaxf(1e-28f, xx2 - xx1);
                    float hh = fmaxf(1e-28f, yy2 - yy1);
                    float inter = ww * hh;
                    float areab = (b.z - b.x) * (b.w - b.y);
                    float iou = inter / (areaa + areab - inter);  // exact ref formula
                    if (iou > 0.5f) atomicAnd(&keepb[j >> 5], ~(1u << (j & 31)));
                }
            }
        }
        __syncthreads();
    }
    for (int r = t; r < NBOX; r += 256) {
        int orig = sidx[r];
        uint32_t kb = (keepb[r >> 5] >> (r & 31)) & 1u;
        out[38400 + orig] = (float)kb;
        out[25600 + orig] = kb ? sscore[r] : 0.0f;
    }
}

extern "C" void kernel_launch(void* const* d_in, const int* in_sizes, int n_in,
                              void* d_out, int out_size, void* d_ws, size_t ws_size,
                              hipStream_t stream) {
    const float* pred = (const float*)d_in[0];
    float* out = (float*)d_out;
    char* ws = (char*)d_ws;
    float4*   boff   = (float4*)(ws + 0);        // 6400 f4  (102400 B)
    float*    score  = (float*)(ws + 102400);    // 6400 f32
    float4*   blkbb  = (float4*)(ws + 128000);   // 100 f4 block bboxes
    uint64_t* validw = (uint64_t*)(ws + 129600); // 100 u64 valid ballots
    uint32_t* flag   = (uint32_t*)(ws + 130432); // 1 u32
    uint32_t* done   = (uint32_t*)(ws + 130436); // 1 u32
    int*      sidx   = (int*)(ws + 131072);      // slow path only
    float*    sscore = (float*)(ws + 156672);    // slow path only
    float4*   sbox   = (float4*)(ws + 182272);   // slow path only

    k_decode<<<25, 256, 0, stream>>>(pred, out, boff, score, blkbb, validw, flag, done);
    k_pairs<<<NBLK, 256, 0, stream>>>(boff, blkbb, validw, score, flag, done,
                                      sidx, sscore, sbox, out);
}